// Round 2
// baseline (423.981 us; speedup 1.0000x reference)
//
#include <hip/hip_runtime.h>

// QuadConv: out[p,:] = concat_j feat[nidx[p,j],:] (K=1152) @ W.T (128x1152) + b
// R2: M-unroll 2 (wave = 2x32 rows, MT=256) to halve LDS B-reads per MFMA,
//     depth-2 software-pipelined A-gather (explicit register stages),
//     double-buffered W LDS slabs (one barrier per j).

#define NPTS    262144
#define CIN     128
#define COUT    128
#define KNBR    9
#define KDIM    (KNBR * CIN)     // 1152
#define NKS     (KDIM / 16)      // 72
#define NFRAGS  (NKS * 4)        // 288 fragments of 1 KiB
#define MT      256              // rows per block: 4 waves x 2 tiles x 32
#define WP_ELEMS (NFRAGS * 512)  // bf16 elements in packed W

typedef __bf16  bf16x8 __attribute__((ext_vector_type(8)));
typedef float   f32x4  __attribute__((ext_vector_type(4)));
typedef float   f32x16 __attribute__((ext_vector_type(16)));

// Pack W [128 x 1152] fp32 -> bf16 MFMA B-fragment order; block 72 zeroes the
// fallback row used for -1 neighbors.
__global__ __launch_bounds__(256) void pack_w_kernel(const float* __restrict__ W,
                                                     __bf16* __restrict__ Wp,
                                                     float* __restrict__ zrow) {
    if (blockIdx.x == NFRAGS / 4) {            // zero-row block
        if (threadIdx.x < CIN) zrow[threadIdx.x] = 0.f;
        return;
    }
    int t    = blockIdx.x * 256 + threadIdx.x;
    int lane = t & 63;
    int frag = t >> 6;
    int nt = frag & 3;
    int ks = frag >> 2;
    int n  = nt * 32 + (lane & 31);
    int k0 = ks * 16 + (lane >> 5) * 8;
    const f32x4* src = (const f32x4*)(W + (size_t)n * KDIM + k0);
    f32x4 v0 = src[0], v1 = src[1];
    bf16x8 o;
#pragma unroll
    for (int i = 0; i < 4; ++i) { o[i] = (__bf16)v0[i]; o[i + 4] = (__bf16)v1[i]; }
    *(bf16x8*)(Wp + (size_t)frag * 512 + lane * 8) = o;
}

struct ARegs { f32x4 r0a, r0b, r1a, r1b; };

__global__ __launch_bounds__(256, 2) void qconv_kernel(
    const float*  __restrict__ feat,   // [NPTS, 128] fp32
    const int*    __restrict__ nidx,   // [NPTS, 9] int32
    const __bf16* __restrict__ Wp,     // packed fragments, 288 KiB
    const float*  __restrict__ zrow,   // 128 zero floats (for -1 neighbors)
    const float*  __restrict__ bias,   // [128]
    float*        __restrict__ out)    // [NPTS, 128]
{
    __shared__ __align__(16) __bf16 lds[2][32 * 512];   // 2 x 32 KiB W slabs

    const int tid  = threadIdx.x;
    const int lane = tid & 63;
    const int wave = tid >> 6;
    const int l31  = lane & 31;
    const int half = lane >> 5;
    const int rb   = blockIdx.x * MT;
    const int p0   = rb + wave * 32 + l31;        // tile0 row this lane gathers
    const int p1   = p0 + 128;                    // tile1 row

    f32x16 acc[8];
#pragma unroll
    for (int a = 0; a < 8; ++a)
#pragma unroll
        for (int i = 0; i < 16; ++i) acc[a][i] = 0.f;

    const int* nrow0 = nidx + (size_t)p0 * KNBR;
    const int* nrow1 = nidx + (size_t)p1 * KNBR;

    auto stage = [&](int j, int buf) {
#pragma unroll
        for (int f8 = 0; f8 < 8; ++f8) {
            const int f = wave * 8 + f8;
            const __bf16* g = Wp + (size_t)(j * 32 + f) * 512 + lane * 8;
            __builtin_amdgcn_global_load_lds(
                (const __attribute__((address_space(1))) void*)g,
                (__attribute__((address_space(3))) void*)(&lds[buf][f * 512 + lane * 8]),
                16, 0, 0);
        }
    };
    auto load_a = [&](const float* a0p, const float* a1p, int ks) -> ARegs {
        const int c0 = ks * 16 + half * 8;
        ARegs A;
        A.r0a = *(const f32x4*)(a0p + c0);
        A.r0b = *(const f32x4*)(a0p + c0 + 4);
        A.r1a = *(const f32x4*)(a1p + c0);
        A.r1b = *(const f32x4*)(a1p + c0 + 4);
        return A;
    };
    auto cvt = [&](f32x4 a, f32x4 b) -> bf16x8 {
        bf16x8 o;
#pragma unroll
        for (int i = 0; i < 4; ++i) { o[i] = (__bf16)a[i]; o[i + 4] = (__bf16)b[i]; }
        return o;
    };

    int gi0 = nrow0[0], gi1 = nrow1[0];
    const float* a0p = (gi0 >= 0) ? feat + (size_t)gi0 * CIN : zrow;
    const float* a1p = (gi1 >= 0) ? feat + (size_t)gi1 * CIN : zrow;

    stage(0, 0);
    ARegs A0 = load_a(a0p, a1p, 0);   // stage for ks=0
    ARegs A1 = load_a(a0p, a1p, 1);   // stage for ks=1
    __syncthreads();                  // drains vmcnt: slab 0 + A prologue

    for (int j = 0; j < KNBR; ++j) {
        const int buf = j & 1;
        if (j + 1 < KNBR) stage(j + 1, buf ^ 1);   // issue early, consumed next j
        // prefetch next neighbor pointers
        int ngi0 = (j + 1 < KNBR) ? nrow0[j + 1] : 0;
        int ngi1 = (j + 1 < KNBR) ? nrow1[j + 1] : 0;
        const float* na0p = (ngi0 >= 0) ? feat + (size_t)ngi0 * CIN : zrow;
        const float* na1p = (ngi1 >= 0) ? feat + (size_t)ngi1 * CIN : zrow;

#pragma unroll
        for (int ks = 0; ks < 8; ++ks) {
            ARegs cur = (ks & 1) ? A1 : A0;
            // prefetch ks+2 (crosses into j+1 for ks>=6)
            if (ks < 6) {
                if (ks & 1) A1 = load_a(a0p, a1p, ks + 2);
                else        A0 = load_a(a0p, a1p, ks + 2);
            } else if (j + 1 < KNBR) {
                if (ks & 1) A1 = load_a(na0p, na1p, ks - 6);
                else        A0 = load_a(na0p, na1p, ks - 6);
            }
            bf16x8 af0 = cvt(cur.r0a, cur.r0b);
            bf16x8 af1 = cvt(cur.r1a, cur.r1b);
#pragma unroll
            for (int nt = 0; nt < 4; ++nt) {
                bf16x8 bfrag = *(const bf16x8*)(&lds[buf][(ks * 4 + nt) * 512 + lane * 8]);
                acc[nt]     = __builtin_amdgcn_mfma_f32_32x32x16_bf16(af0, bfrag, acc[nt], 0, 0, 0);
                acc[4 + nt] = __builtin_amdgcn_mfma_f32_32x32x16_bf16(af1, bfrag, acc[4 + nt], 0, 0, 0);
            }
        }
        a0p = na0p; a1p = na1p;
        __syncthreads();   // buf reuse fence + drains staging for j+1
    }

    // Epilogue: C/D layout col=lane&31, row=(r&3)+8*(r>>2)+4*half  [m74/m101]
#pragma unroll
    for (int nt = 0; nt < 4; ++nt) {
        const int col = nt * 32 + l31;
        const float bv = bias[col];
#pragma unroll
        for (int r = 0; r < 16; ++r) {
            const int row = (r & 3) + 8 * (r >> 2) + 4 * half;
            out[(size_t)(rb + wave * 32 + row) * COUT + col]       = acc[nt][r] + bv;
            out[(size_t)(rb + 128 + wave * 32 + row) * COUT + col] = acc[4 + nt][r] + bv;
        }
    }
}

extern "C" void kernel_launch(void* const* d_in, const int* in_sizes, int n_in,
                              void* d_out, int out_size, void* d_ws, size_t ws_size,
                              hipStream_t stream) {
    const float* feat = (const float*)d_in[0];
    const int*   nidx = (const int*)d_in[1];
    const float* W    = (const float*)d_in[2];
    const float* bias = (const float*)d_in[3];
    float*       out  = (float*)d_out;
    __bf16*      Wp   = (__bf16*)d_ws;                       // 288 KiB
    float*       zrow = (float*)((char*)d_ws + WP_ELEMS * 2); // +512 B

    pack_w_kernel<<<NFRAGS / 4 + 1, 256, 0, stream>>>(W, Wp, zrow);
    qconv_kernel<<<NPTS / MT, 256, 0, stream>>>(feat, nidx, Wp, zrow, bias, out);
}

// Round 3
// 372.277 us; speedup vs baseline: 1.1389x; 1.1389x over previous
//
#include <hip/hip_runtime.h>

// QuadConv: out[p,:] = concat_j feat[nidx[p,j],:] (K=1152) @ W.T (128x1152) + b
// R3: barrier-free MFMA kernel. No LDS at all: W B-fragments read coalesced from
// global (L1/L2-resident 288 KB), A gathered from a bf16 pre-converted copy of
// features. Fully unrolled 72-step K-loop with register rings: B depth-3
// (issue dist 2), A depth-4 (issue dist 4). M-unroll 2 (wave = 2x32 rows).

#define NPTS    262144
#define CIN     128
#define COUT    128
#define KNBR    9
#define KDIM    (KNBR * CIN)     // 1152
#define NKS     (KDIM / 16)      // 72 K-steps of 16
#define NFRAGS  (NKS * 4)        // 288 B-fragments of 1 KiB
#define MT      256              // rows per block: 4 waves x 2 tiles x 32

typedef __bf16  bf16x8 __attribute__((ext_vector_type(8)));
typedef float   f32x4  __attribute__((ext_vector_type(4)));
typedef float   f32x16 __attribute__((ext_vector_type(16)));

// ---- pre-pass 1: features fp32 -> bf16 (halves gather traffic) ----
__global__ __launch_bounds__(256) void convert_feat_kernel(const float* __restrict__ f,
                                                           __bf16* __restrict__ fb) {
    size_t i = ((size_t)blockIdx.x * 256 + threadIdx.x) * 8;
    f32x4 a = *(const f32x4*)(f + i);
    f32x4 b = *(const f32x4*)(f + i + 4);
    bf16x8 o;
#pragma unroll
    for (int k = 0; k < 4; ++k) { o[k] = (__bf16)a[k]; o[k + 4] = (__bf16)b[k]; }
    *(bf16x8*)(fb + i) = o;
}

// ---- pre-pass 2: W [128 x 1152] fp32 -> bf16 MFMA B-fragment order ----
// frag = ks*4 + nt; elem(frag*512 + lane*8 + i) = W[nt*32+(lane&31)][ks*16+(lane>>5)*8+i]
// Last block zeroes the fallback rows used for -1 neighbors.
__global__ __launch_bounds__(256) void pack_w_kernel(const float* __restrict__ W,
                                                     __bf16* __restrict__ Wp,
                                                     float* __restrict__ zrow_f,
                                                     __bf16* __restrict__ zrow_b) {
    if (blockIdx.x == NFRAGS / 4) {
        int t = threadIdx.x;
        if (t < 128) zrow_f[t] = 0.f;
        else         zrow_b[t - 128] = (__bf16)0.f;
        return;
    }
    int t    = blockIdx.x * 256 + threadIdx.x;
    int lane = t & 63;
    int frag = t >> 6;
    int nt = frag & 3;
    int ks = frag >> 2;
    int n  = nt * 32 + (lane & 31);
    int k0 = ks * 16 + (lane >> 5) * 8;
    const f32x4* src = (const f32x4*)(W + (size_t)n * KDIM + k0);
    f32x4 v0 = src[0], v1 = src[1];
    bf16x8 o;
#pragma unroll
    for (int i = 0; i < 4; ++i) { o[i] = (__bf16)v0[i]; o[i + 4] = (__bf16)v1[i]; }
    *(bf16x8*)(Wp + (size_t)frag * 512 + lane * 8) = o;
}

// ---- main kernel: barrier-free, LDS-free ----
template <bool BF16A, typename AT>
__global__ __launch_bounds__(256, 2) void qconv_kernel(
    const AT*     __restrict__ featA,  // [NPTS,128] bf16 (or f32 fallback)
    const int*    __restrict__ nidx,   // [NPTS,9]
    const __bf16* __restrict__ Wp,     // packed B-fragments, 288 KiB
    const AT*     __restrict__ zrow,   // 128 zeros (for -1 neighbors)
    const float*  __restrict__ bias,   // [128]
    float*        __restrict__ out)    // [NPTS,128]
{
    const int tid  = threadIdx.x;
    const int lane = tid & 63;
    const int wave = tid >> 6;
    const int l31  = lane & 31;
    const int half = lane >> 5;
    const int rb   = blockIdx.x * MT;
    const int p0   = rb + wave * 32 + l31;   // tile0 row for this lane
    const int p1   = p0 + 128;               // tile1 row

    const int* n0 = nidx + (size_t)p0 * KNBR;
    const int* n1 = nidx + (size_t)p1 * KNBR;
    const AT* pa0[KNBR];
    const AT* pa1[KNBR];
#pragma unroll
    for (int j = 0; j < KNBR; ++j) {
        int g0 = n0[j], g1 = n1[j];
        pa0[j] = (g0 >= 0) ? featA + (size_t)g0 * CIN : zrow;
        pa1[j] = (g1 >= 0) ? featA + (size_t)g1 * CIN : zrow;
    }

    f32x16 acc[8];
#pragma unroll
    for (int a = 0; a < 8; ++a)
#pragma unroll
        for (int i = 0; i < 16; ++i) acc[a][i] = 0.f;

    constexpr int AD = BF16A ? 4 : 2;            // A-ring depth
    bf16x8 AbB[BF16A ? AD : 1][2];               // bf16 A ring
    f32x4  AbF[BF16A ? 1 : AD][2][2];            // f32 A ring (fallback)
    bf16x8 Bb[3][4];                             // B ring, depth 3

    auto issueA = [&](int t) {
        const int j = t >> 3, kk = t & 7;
        const int off = kk * 16 + half * 8;      // elements within the row
        if constexpr (BF16A) {
            AbB[t % AD][0] = *(const bf16x8*)((const __bf16*)pa0[j] + off);
            AbB[t % AD][1] = *(const bf16x8*)((const __bf16*)pa1[j] + off);
        } else {
            AbF[t % AD][0][0] = *(const f32x4*)((const float*)pa0[j] + off);
            AbF[t % AD][0][1] = *(const f32x4*)((const float*)pa0[j] + off + 4);
            AbF[t % AD][1][0] = *(const f32x4*)((const float*)pa1[j] + off);
            AbF[t % AD][1][1] = *(const f32x4*)((const float*)pa1[j] + off + 4);
        }
    };
    auto getA = [&](int t, int tile) -> bf16x8 {
        if constexpr (BF16A) {
            return AbB[t % AD][tile];
        } else {
            f32x4 x = AbF[t % AD][tile][0], y = AbF[t % AD][tile][1];
            bf16x8 o;
#pragma unroll
            for (int k = 0; k < 4; ++k) { o[k] = (__bf16)x[k]; o[k + 4] = (__bf16)y[k]; }
            return o;
        }
    };
    auto issueB = [&](int t) {
#pragma unroll
        for (int nt = 0; nt < 4; ++nt)
            Bb[t % 3][nt] = *(const bf16x8*)(Wp + (size_t)(t * 4 + nt) * 512 + lane * 8);
    };

    // prologue
    issueA(0); issueA(1);
    if constexpr (BF16A) { issueA(2); issueA(3); }
    issueB(0); issueB(1);

#pragma unroll
    for (int t = 0; t < NKS; ++t) {
        if (t + 2 < NKS) issueB(t + 2);          // dist-2, ring-3: no collision
        bf16x8 a0 = getA(t, 0);
        bf16x8 a1 = getA(t, 1);
#pragma unroll
        for (int nt = 0; nt < 4; ++nt) {
            acc[nt]     = __builtin_amdgcn_mfma_f32_32x32x16_bf16(a0, Bb[t % 3][nt], acc[nt], 0, 0, 0);
            acc[4 + nt] = __builtin_amdgcn_mfma_f32_32x32x16_bf16(a1, Bb[t % 3][nt], acc[4 + nt], 0, 0, 0);
        }
        if (t + AD < NKS) issueA(t + AD);        // WAR after consume: ring-AD safe
    }

    // epilogue: C/D layout col=lane&31, row=(r&3)+8*(r>>2)+4*half  [m74/m101]
#pragma unroll
    for (int nt = 0; nt < 4; ++nt) {
        const int col = nt * 32 + l31;
        const float bv = bias[col];
#pragma unroll
        for (int r = 0; r < 16; ++r) {
            const int row = (r & 3) + 8 * (r >> 2) + 4 * half;
            out[(size_t)(rb + wave * 32 + row) * COUT + col]       = acc[nt][r] + bv;
            out[(size_t)(rb + 128 + wave * 32 + row) * COUT + col] = acc[4 + nt][r] + bv;
        }
    }
}

extern "C" void kernel_launch(void* const* d_in, const int* in_sizes, int n_in,
                              void* d_out, int out_size, void* d_ws, size_t ws_size,
                              hipStream_t stream) {
    const float* feat = (const float*)d_in[0];
    const int*   nidx = (const int*)d_in[1];
    const float* W    = (const float*)d_in[2];
    const float* bias = (const float*)d_in[3];
    float*       out  = (float*)d_out;

    const size_t FEATB_BYTES = (size_t)NPTS * CIN * 2;      // 64 MiB
    const size_t WP_BYTES    = (size_t)NFRAGS * 512 * 2;    // 288 KiB

    if (ws_size >= FEATB_BYTES + WP_BYTES + 1024) {
        __bf16* featb  = (__bf16*)d_ws;
        __bf16* Wp     = (__bf16*)((char*)d_ws + FEATB_BYTES);
        float*  zrow_f = (float*)((char*)d_ws + FEATB_BYTES + WP_BYTES);
        __bf16* zrow_b = (__bf16*)((char*)d_ws + FEATB_BYTES + WP_BYTES + 512);
        convert_feat_kernel<<<NPTS * CIN / (256 * 8), 256, 0, stream>>>(feat, featb);
        pack_w_kernel<<<NFRAGS / 4 + 1, 256, 0, stream>>>(W, Wp, zrow_f, zrow_b);
        qconv_kernel<true, __bf16><<<NPTS / MT, 256, 0, stream>>>(featb, nidx, Wp, zrow_b, bias, out);
    } else {
        __bf16* Wp     = (__bf16*)d_ws;
        float*  zrow_f = (float*)((char*)d_ws + WP_BYTES);
        __bf16* zrow_b = (__bf16*)((char*)d_ws + WP_BYTES + 512);
        pack_w_kernel<<<NFRAGS / 4 + 1, 256, 0, stream>>>(W, Wp, zrow_f, zrow_b);
        qconv_kernel<false, float><<<NPTS / MT, 256, 0, stream>>>(feat, nidx, Wp, zrow_f, bias, out);
    }
}

// Round 4
// 367.372 us; speedup vs baseline: 1.1541x; 1.0134x over previous
//
#include <hip/hip_runtime.h>

// QuadConv R4: barrier-free MFMA GEMM with AITER-style pipelined K-loop.
//  - A (gathered neighbor features, bf16) staged into per-wave-private LDS via
//    global_load_lds, full-cache-line coalesced (8 lanes x 16B per row window),
//    XOR-swizzled so fragment ds_read_b128 is bank-conflict-free.
//  - Manual s_waitcnt(vmcnt) with statically counted issue schedule; no
//    __syncthreads anywhere (no vmcnt(0) drains).
//  - B (packed W fragments) register ring from global, dist-2/ring-3.
//  - M-unroll 2: wave owns rows [wave*32, +32) and +128.

#define NPTS    262144
#define CIN     128
#define COUT    128
#define KNBR    9
#define KDIM    1152
#define NKS     72
#define NFRAGS  288
#define NFRAGS_PAD 296            // +2 t-groups so B(t+2) needs no guard
#define MT      256

typedef __bf16  bf16x8 __attribute__((ext_vector_type(8)));
typedef float   f32x4  __attribute__((ext_vector_type(4)));
typedef float   f32x16 __attribute__((ext_vector_type(16)));

// s_waitcnt imm: vmcnt[3:0]@[3:0], vmcnt[5:4]@[15:14], exp=7, lgkm=15 (no wait)
#define VMCNT(n) (((n) & 0xF) | (((n) >> 4) << 14) | (0xF << 8) | (7 << 4))

// ---- pre-pass 1: features fp32 -> bf16 ----
__global__ __launch_bounds__(256) void convert_feat_kernel(const float* __restrict__ f,
                                                           __bf16* __restrict__ fb) {
    size_t i = ((size_t)blockIdx.x * 256 + threadIdx.x) * 8;
    f32x4 a = *(const f32x4*)(f + i);
    f32x4 b = *(const f32x4*)(f + i + 4);
    bf16x8 o;
#pragma unroll
    for (int k = 0; k < 4; ++k) { o[k] = (__bf16)a[k]; o[k + 4] = (__bf16)b[k]; }
    *(bf16x8*)(fb + i) = o;
}

// ---- pre-pass 2: W -> bf16 MFMA B-fragment order (+ zero rows) ----
__global__ __launch_bounds__(256) void pack_w_kernel(const float* __restrict__ W,
                                                     __bf16* __restrict__ Wp,
                                                     __bf16* __restrict__ zrow_b) {
    if (blockIdx.x == NFRAGS / 4) {
        int t = threadIdx.x;
        if (t < CIN) zrow_b[t] = (__bf16)0.f;
        return;
    }
    int t    = blockIdx.x * 256 + threadIdx.x;
    int lane = t & 63;
    int frag = t >> 6;
    int nt = frag & 3;
    int ks = frag >> 2;
    int n  = nt * 32 + (lane & 31);
    int k0 = ks * 16 + (lane >> 5) * 8;
    const f32x4* src = (const f32x4*)(W + (size_t)n * KDIM + k0);
    f32x4 v0 = src[0], v1 = src[1];
    bf16x8 o;
#pragma unroll
    for (int i = 0; i < 4; ++i) { o[i] = (__bf16)v0[i]; o[i + 4] = (__bf16)v1[i]; }
    *(bf16x8*)(Wp + (size_t)frag * 512 + lane * 8) = o;
}

// ---- main kernel ----
__global__ __launch_bounds__(256, 2) void qconv_kernel(
    const __bf16* __restrict__ featb,  // [NPTS,128] bf16
    const int*    __restrict__ nidx,   // [NPTS,9]
    const __bf16* __restrict__ Wp,     // packed B-fragments (padded)
    const __bf16* __restrict__ zrow,   // 128 bf16 zeros
    const float*  __restrict__ bias,
    float*        __restrict__ out)
{
    // per-wave: 2 bufs x 2 tiles x 4 KB (32 rows x 128 B half-row windows)
    __shared__ __align__(16) char lds_raw[4 * 2 * 2 * 4096];

    const int tid  = threadIdx.x;
    const int lane = tid & 63;
    const int wave = tid >> 6;
    const int l31  = lane & 31;
    const int half = lane >> 5;
    const int rb   = blockIdx.x * MT;
    char* myLds = lds_raw + wave * 16384;

    // staging role: 8 lanes per row, lane covers swizzled 16B chunk of 128B window
    const int srow = lane >> 3;   // row within 8-row group
    const int schk = lane & 7;    // LDS slot; fetches global chunk schk^srow

    // idx base addresses for the 8 staged row-groups (n = T*4 + i)
    const int* ia[8];
#pragma unroll
    for (int n = 0; n < 8; ++n) {
        int rg = rb + (n >> 2) * 128 + wave * 32 + (n & 3) * 8 + srow;
        ia[n] = nidx + (size_t)rg * KNBR;
    }

    f32x16 acc[8];
#pragma unroll
    for (int a = 0; a < 8; ++a)
#pragma unroll
        for (int i = 0; i < 16; ++i) acc[a][i] = 0.f;

    const __bf16* Pst[8];   // row pointers for the j currently being staged
    int NPidx[8];           // raw indices for next j
    bf16x8 Bb[3][4];        // B register ring

    auto convertP = [&](void) {
#pragma unroll
        for (int n = 0; n < 8; ++n)
            Pst[n] = (NPidx[n] >= 0) ? featb + (size_t)NPidx[n] * CIN : zrow;
    };
    // stage chunk c (ks [4c,4c+4)): 8 fire-and-forget 1KB global_load_lds
    auto stage_chunk = [&](int c) {
        const int buf  = c & 1;                  // also the half-row byte sel
        const int eoff = (c & 1) * 64 + (schk ^ srow) * 8;   // bf16 elems
#pragma unroll
        for (int n = 0; n < 8; ++n) {
            const int T = n >> 2, i = n & 3;
            const __bf16* g = Pst[n] + eoff;
            char* dst = myLds + buf * 8192 + T * 4096 + i * 1024;
            __builtin_amdgcn_global_load_lds(
                (const __attribute__((address_space(1))) void*)g,
                (__attribute__((address_space(3))) void*)dst,
                16, 0, 0);
        }
    };
    auto issueB = [&](int t) {
#pragma unroll
        for (int nt = 0; nt < 4; ++nt)
            Bb[t % 3][nt] = *(const bf16x8*)(Wp + (size_t)(t * 4 + nt) * 512 + lane * 8);
    };
    auto readA = [&](int buf, int T, int ksl) -> bf16x8 {
        const int s = (ksl * 2 + half) ^ (l31 & 7);
        return *(const bf16x8*)(myLds + buf * 8192 + T * 4096 + l31 * 128 + s * 16);
    };

    // ---- prologue ----
#pragma unroll
    for (int n = 0; n < 8; ++n) NPidx[n] = ia[n][0];   // j = 0
    convertP();
    __builtin_amdgcn_sched_barrier(0);
    stage_chunk(0);
    __builtin_amdgcn_sched_barrier(0);
    issueB(0); issueB(1);

    // ---- main loop: 9 j's x 2 chunks; fully unrolled for constant vmcnt ----
#pragma unroll
    for (int j = 0; j < KNBR; ++j) {
        // ===== even chunk c = 2j =====
        __builtin_amdgcn_sched_barrier(0);
        if (j == 0) __builtin_amdgcn_s_waitcnt(VMCNT(8));   // after stage(0): B x8
        else        __builtin_amdgcn_s_waitcnt(VMCNT(16));  // after stage(2j): B x16
        __builtin_amdgcn_sched_barrier(0);
        stage_chunk(2 * j + 1);                             // odd chunk, same j
        __builtin_amdgcn_sched_barrier(0);
        {
            const int jn = (j + 1 < KNBR) ? j + 1 : KNBR - 1;
#pragma unroll
            for (int n = 0; n < 8; ++n) NPidx[n] = ia[n][jn];   // 8 vmem
#pragma unroll
            for (int ksl = 0; ksl < 4; ++ksl) {
                const int t = j * 8 + ksl;
                issueB(t + 2);                                   // 4 vmem
                bf16x8 a0 = readA(0, 0, ksl);
                bf16x8 a1 = readA(0, 1, ksl);
#pragma unroll
                for (int nt = 0; nt < 4; ++nt) {
                    acc[nt]     = __builtin_amdgcn_mfma_f32_32x32x16_bf16(a0, Bb[t % 3][nt], acc[nt], 0, 0, 0);
                    acc[4 + nt] = __builtin_amdgcn_mfma_f32_32x32x16_bf16(a1, Bb[t % 3][nt], acc[4 + nt], 0, 0, 0);
                }
            }
        }
        // ===== odd chunk c = 2j+1 =====
        __builtin_amdgcn_sched_barrier(0);
        __builtin_amdgcn_s_waitcnt(VMCNT(24));   // after stage(2j+1): idx x8 + B x16
        __builtin_amdgcn_sched_barrier(0);
        convertP();                              // NPidx ~1 chunk old
        stage_chunk(2 * j + 2);                  // even chunk of next j (j=8: dummy)
        __builtin_amdgcn_sched_barrier(0);
#pragma unroll
        for (int ksl = 4; ksl < 8; ++ksl) {
            const int t = j * 8 + ksl;
            issueB(t + 2);
            bf16x8 a0 = readA(1, 0, ksl - 4);
            bf16x8 a1 = readA(1, 1, ksl - 4);
#pragma unroll
            for (int nt = 0; nt < 4; ++nt) {
                acc[nt]     = __builtin_amdgcn_mfma_f32_32x32x16_bf16(a0, Bb[t % 3][nt], acc[nt], 0, 0, 0);
                acc[4 + nt] = __builtin_amdgcn_mfma_f32_32x32x16_bf16(a1, Bb[t % 3][nt], acc[4 + nt], 0, 0, 0);
            }
        }
    }

    // ---- epilogue: C/D layout col=lane&31, row=(r&3)+8*(r>>2)+4*half ----
#pragma unroll
    for (int nt = 0; nt < 4; ++nt) {
        const int col = nt * 32 + l31;
        const float bv = bias[col];
#pragma unroll
        for (int r = 0; r < 16; ++r) {
            const int row = (r & 3) + 8 * (r >> 2) + 4 * half;
            out[(size_t)(rb + wave * 32 + row) * COUT + col]       = acc[nt][r] + bv;
            out[(size_t)(rb + 128 + wave * 32 + row) * COUT + col] = acc[4 + nt][r] + bv;
        }
    }
}

// ---- safety fallback (never expected to run; ws_size has been ~>64MiB) ----
__global__ void qconv_naive(const float* __restrict__ feat, const int* __restrict__ nidx,
                            const float* __restrict__ W, const float* __restrict__ bias,
                            float* __restrict__ out) {
    int p = blockIdx.x, c = threadIdx.x;
    float s = bias[c];
    for (int j = 0; j < KNBR; ++j) {
        int g = nidx[(size_t)p * KNBR + j];
        if (g < 0) continue;
        const float* fr = feat + (size_t)g * CIN;
        const float* wr = W + (size_t)c * KDIM + j * CIN;
        for (int k = 0; k < CIN; ++k) s += fr[k] * wr[k];
    }
    out[(size_t)p * COUT + c] = s;
}

extern "C" void kernel_launch(void* const* d_in, const int* in_sizes, int n_in,
                              void* d_out, int out_size, void* d_ws, size_t ws_size,
                              hipStream_t stream) {
    const float* feat = (const float*)d_in[0];
    const int*   nidx = (const int*)d_in[1];
    const float* W    = (const float*)d_in[2];
    const float* bias = (const float*)d_in[3];
    float*       out  = (float*)d_out;

    const size_t FEATB_BYTES = (size_t)NPTS * CIN * 2;        // 64 MiB
    const size_t WP_BYTES    = (size_t)NFRAGS_PAD * 512 * 2;  // 296 KiB

    if (ws_size >= FEATB_BYTES + WP_BYTES + 512) {
        __bf16* featb  = (__bf16*)d_ws;
        __bf16* Wp     = (__bf16*)((char*)d_ws + FEATB_BYTES);
        __bf16* zrow_b = (__bf16*)((char*)d_ws + FEATB_BYTES + WP_BYTES);
        convert_feat_kernel<<<NPTS * CIN / (256 * 8), 256, 0, stream>>>(feat, featb);
        pack_w_kernel<<<NFRAGS / 4 + 1, 256, 0, stream>>>(W, Wp, zrow_b);
        qconv_kernel<<<NPTS / MT, 256, 0, stream>>>(featb, nidx, Wp, zrow_b, bias, out);
    } else {
        qconv_naive<<<NPTS, COUT, 0, stream>>>(feat, nidx, W, bias, out);
    }
}